// Round 17
// baseline (247.941 us; speedup 1.0000x reference)
//
#include <hip/hip_runtime.h>
#include <math.h>

#define Bn 512
#define Sn 1024
#define Tn 48
#define NSEG 8
#define SEGLEN 128

typedef _Float16 h2 __attribute__((ext_vector_type(2)));
typedef _Float16 h4 __attribute__((ext_vector_type(4)));
typedef _Float16 h8 __attribute__((ext_vector_type(8)));
typedef float    f4 __attribute__((ext_vector_type(4)));

static constexpr float LOG2E = 1.4426950408889634f;
static constexpr float LN2f  = 0.6931471805599453f;

// gfx950-native K=32 f16 MFMA (~5cyc vs ~18cyc for the legacy 16x16x16 —
// rounds 6/9/13/15 all conserved dur*MfmaUtil ~= 100us: the old shape's
// pipe-work floor. This shape cuts the floor 5x).
#define MFMA32(A, B, C) __builtin_amdgcn_mfma_f32_16x16x32_f16((A), (B), (C), 0, 0, 0)

__device__ __forceinline__ h2 hmax2(h2 a, h2 b) {
#if __has_builtin(__builtin_elementwise_max)
  return __builtin_elementwise_max(a, b);
#else
  h2 r;
  r[0] = a[0] > b[0] ? a[0] : b[0];
  r[1] = a[1] > b[1] ? a[1] : b[1];
  return r;
#endif
}
__device__ __forceinline__ h2 cvt2(float a, float b) {
  return __builtin_bit_cast(h2, __builtin_amdgcn_cvt_pkrtz(a, b));
}
__device__ __forceinline__ h4 mkh4(h2 lo, h2 hi) {
  return __builtin_shufflevector(lo, hi, 0, 1, 2, 3);
}
__device__ __forceinline__ h2 loh(h4 v) { return __builtin_shufflevector(v, v, 0, 1); }
__device__ __forceinline__ h2 hih(h4 v) { return __builtin_shufflevector(v, v, 2, 3); }
__device__ __forceinline__ h8 mk8(h2 a, h2 b, h2 c, h2 d) {
  h8 r;
  r[0] = a[0]; r[1] = a[1]; r[2] = b[0]; r[3] = b[1];
  r[4] = c[0]; r[5] = c[1]; r[6] = d[0]; r[7] = d[1];
  return r;
}

// Memory-bound pregen: ehat[b][s][k] = f16(2^(em*log2e - 6)) (RTN converts).
__global__ __launch_bounds__(256) void ehgen(const float* __restrict__ em,
                                             _Float16* __restrict__ out) {
  const size_t total = (size_t)Bn * Sn * Tn;
  const size_t i = ((size_t)blockIdx.x * 256 + threadIdx.x) * 8;
  if (i >= total) return;
  const f4 a = *(const f4*)(em + i);
  const f4 b = *(const f4*)(em + i + 4);
  h4 o1, o2;
  #pragma unroll
  for (int j = 0; j < 4; ++j) {
    o1[j] = (_Float16)__builtin_amdgcn_exp2f(fmaf(a[j], LOG2E, -6.0f));
    o2[j] = (_Float16)__builtin_amdgcn_exp2f(fmaf(b[j], LOG2E, -6.0f));
  }
  *(h4*)(out + i) = o1;
  *(h4*)(out + i + 4) = o2;
}

// Segment-parallel CRF forward, two chains/wave, 256-thread blocks,
// 16x16x32_f16 MFMA with K=48 padded to 64 (2 K-tiles of 32).
// Fragment k-mapping (from the m156 tr_read layout): 8-elem operand = two
// stacked K=16 halves: elems 0-3 <-> k=4g+i, elems 4-7 <-> k=16+4g+(i-4).
// D layout (HW-verified): row=4g+i (within 16-row tile), col=c16 — so
// Bnext[0][ct]={Dtile0,Dtile1}, Bnext[1][ct]={Dtile2, 0pad}; A k>=48 pad = 0.
template <bool PRE>
__global__ __launch_bounds__(256, 1)
void crf_fwd_seg(const float* __restrict__ em,
                 const float* __restrict__ mask,
                 const float* __restrict__ trans,
                 const float* __restrict__ startt,
                 const float* __restrict__ endt,
                 const _Float16* __restrict__ eh16,
                 float* __restrict__ den_out)
{
  const int b   = blockIdx.x;
  const int tid = threadIdx.x;
  const int wid = tid >> 6;     // wave id 0..3 -> segments 2wid, 2wid+1
  const int l   = tid & 63;
  const int c16 = l & 15;       // column within a 16-col tile
  const int g   = l >> 4;       // row/k group: rows 4g..4g+3

  __shared__ float lwbuf[64];   // running log2 state for the combine

  const float*    __restrict__ emb = em + (size_t)b * Sn * Tn;
  const float*    __restrict__ mkb = mask + (size_t)b * Sn;
  const _Float16* __restrict__ ehL = PRE ? (eh16 + (size_t)b * Sn * Tn + 4 * g) : nullptr;
  const float*    __restrict__ emL = emb + 4 * g;

  // ---- static A fragments (2 K-tiles of 32) + global trans max ----
  h8 Afr[3][2];
  float mtg;
  {
    float tl[3][3][4];
    float mt = -1e30f;
    #pragma unroll
    for (int rt = 0; rt < 3; ++rt)
      #pragma unroll
      for (int kt = 0; kt < 3; ++kt) {
        const f4 t4 = *(const f4*)(trans + (16 * rt + c16) * Tn + 16 * kt + 4 * g);
        #pragma unroll
        for (int i = 0; i < 4; ++i) {
          const float v = t4[i] * LOG2E;
          tl[rt][kt][i] = v;
          mt = fmaxf(mt, v);
        }
      }
    #pragma unroll
    for (int off = 1; off < 64; off <<= 1) mt = fmaxf(mt, __shfl_xor(mt, off));
    mtg = mt;
    #pragma unroll
    for (int rt = 0; rt < 3; ++rt) {
      h8 a0, a1;
      #pragma unroll
      for (int i = 0; i < 4; ++i) {
        a0[i]     = (_Float16)__builtin_amdgcn_exp2f(tl[rt][0][i] - mtg);
        a0[i + 4] = (_Float16)__builtin_amdgcn_exp2f(tl[rt][1][i] - mtg);
        a1[i]     = (_Float16)__builtin_amdgcn_exp2f(tl[rt][2][i] - mtg);
        a1[i + 4] = (_Float16)0.0f;   // k 48..63 pad (multiplicative zero)
      }
      Afr[rt][0] = a0;
      Afr[rt][1] = a1;
    }
  }

  // ---- two chain states: W = I, stored as B-fragments [kt2][ct] ----
  h8 BfA[2][3], BfB[2][3];
  float McA[3] = {0.f, 0.f, 0.f}, McB[3] = {0.f, 0.f, 0.f};
  float cntA = 0.f, cntB = 0.f;
  #pragma unroll
  for (int kt2 = 0; kt2 < 2; ++kt2)
    #pragma unroll
    for (int ct = 0; ct < 3; ++ct) {
      h8 r;
      #pragma unroll
      for (int i = 0; i < 8; ++i) {
        const int k = 32 * kt2 + ((i < 4) ? (4 * g + i) : (16 + 4 * g + (i - 4)));
        r[i] = (_Float16)((k == 16 * ct + c16) ? 1.0f : 0.0f);
      }
      BfA[kt2][ct] = r;
      BfB[kt2][ct] = r;
    }

  auto loadEH = [&](int s, h4& x, h4& y, h4& z) {
    if constexpr (PRE) {
      const _Float16* p = ehL + (size_t)s * Tn;
      x = *(const h4*)(p);
      y = *(const h4*)(p + 16);
      z = *(const h4*)(p + 32);
    } else {
      const float* p = emL + (size_t)s * Tn;
      const f4 a = *(const f4*)(p);
      const f4 b2 = *(const f4*)(p + 16);
      const f4 c2 = *(const f4*)(p + 32);
      f4 ea, eb2, ec;
      #pragma unroll
      for (int i = 0; i < 4; ++i) {
        ea[i]  = __builtin_amdgcn_exp2f(fmaf(a[i],  LOG2E, -6.0f));
        eb2[i] = __builtin_amdgcn_exp2f(fmaf(b2[i], LOG2E, -6.0f));
        ec[i]  = __builtin_amdgcn_exp2f(fmaf(c2[i], LOG2E, -6.0f));
      }
      x = mkh4(cvt2(ea[0], ea[1]), cvt2(ea[2], ea[3]));
      y = mkh4(cvt2(eb2[0], eb2[1]), cvt2(eb2[2], eb2[3]));
      z = mkh4(cvt2(ec[0], ec[1]), cvt2(ec[2], ec[3]));
    }
  };

  // One recurrence step: MFMAs unguarded (single schedulable block);
  // tail (state/bookkeeping update) mask-guarded -> semantics unchanged.
  auto STEP = [&](h8 (&Bf)[2][3], float (&Mc)[3], float& cnt, int s, float mkval,
                  bool APPLY, const float (&shv)[3]) {
    h4 e0, e1, e2;
    loadEH(s, e0, e1, e2);
    f4 acc[3][3];
    #pragma unroll
    for (int rt = 0; rt < 3; ++rt)
      #pragma unroll
      for (int ct = 0; ct < 3; ++ct) acc[rt][ct] = f4{0.f, 0.f, 0.f, 0.f};
    #pragma unroll
    for (int kt2 = 0; kt2 < 2; ++kt2)
      #pragma unroll
      for (int rt = 0; rt < 3; ++rt)
        #pragma unroll
        for (int ct = 0; ct < 3; ++ct)
          acc[rt][ct] = MFMA32(Afr[rt][kt2], Bf[kt2][ct], acc[rt][ct]);
    if (__int_as_float(__builtin_amdgcn_readfirstlane(__float_as_int(mkval))) > 0.0f) {
      float scv[3];
      if (APPLY) {
        #pragma unroll
        for (int ct = 0; ct < 3; ++ct)
          scv[ct] = __int_as_float((127 - (int)shv[ct]) << 23);  // exact 2^-sh
      }
      const h2 e0l = loh(e0), e0h = hih(e0);
      const h2 e1l = loh(e1), e1h = hih(e1);
      const h2 e2l = loh(e2), e2h = hih(e2);
      const h2 zz2 = h2{(_Float16)0.0f, (_Float16)0.0f};
      #pragma unroll
      for (int ct = 0; ct < 3; ++ct) {
        f4 a0 = acc[0][ct], a1 = acc[1][ct], a2 = acc[2][ct];
        if (APPLY) {
          #pragma unroll
          for (int i = 0; i < 4; ++i) {
            a0[i] *= scv[ct]; a1[i] *= scv[ct]; a2[i] *= scv[ct];
          }
        }
        const h2 lo0 = cvt2(a0[0], a0[1]) * e0l, hi0 = cvt2(a0[2], a0[3]) * e0h;
        const h2 lo1 = cvt2(a1[0], a1[1]) * e1l, hi1 = cvt2(a1[2], a1[3]) * e1h;
        const h2 lo2 = cvt2(a2[0], a2[1]) * e2l, hi2 = cvt2(a2[2], a2[3]) * e2h;
        Bf[0][ct] = mk8(lo0, hi0, lo1, hi1);   // k 0..31  (rows 0..31)
        Bf[1][ct] = mk8(lo2, hi2, zz2, zz2);   // k 32..47 + zero pad
      }
      if (APPLY) { Mc[0] += shv[0]; Mc[1] += shv[1]; Mc[2] += shv[2]; }
      cnt += 1.0f;
    }
  };

  auto MEASURE = [&](h8 (&Bf)[2][3], float (&sh)[3]) {
    #pragma unroll
    for (int ct = 0; ct < 3; ++ct) {
      h2 m = h2{Bf[0][ct][0], Bf[0][ct][1]};
      m = hmax2(m, h2{Bf[0][ct][2], Bf[0][ct][3]});
      m = hmax2(m, h2{Bf[0][ct][4], Bf[0][ct][5]});
      m = hmax2(m, h2{Bf[0][ct][6], Bf[0][ct][7]});
      m = hmax2(m, h2{Bf[1][ct][0], Bf[1][ct][1]});
      m = hmax2(m, h2{Bf[1][ct][2], Bf[1][ct][3]});
      m = hmax2(m, __builtin_bit_cast(h2, __shfl_xor(__builtin_bit_cast(int, m), 16)));
      m = hmax2(m, __builtin_bit_cast(h2, __shfl_xor(__builtin_bit_cast(int, m), 32)));
      const float mf = fmaxf((float)m[0], (float)m[1]);
      int eb = ((__float_as_int(mf) >> 23) & 0xff) - 127;
      eb = eb < -15 ? -15 : (eb > 15 ? 15 : eb);
      sh[ct] = (float)eb;
    }
  };

  // chain A = segment 2wid (steps sA..sA+127), chain B = segment 2wid+1
  // (steps sB..sB+127; wid 3's chain B ends at 1023 -> 127 steps, guarded).
  float shPA[3] = {0.f, 0.f, 0.f}, shAA[3] = {0.f, 0.f, 0.f};
  float shPB[3] = {0.f, 0.f, 0.f}, shAB[3] = {0.f, 0.f, 0.f};
  int sA = 1 + 2 * SEGLEN * wid;
  int sB = sA + SEGLEN;
  f4 mkA = *(const f4*)(mkb + sA);
  f4 mkB = *(const f4*)(mkb + sB);
  f4 mknA, mknB;
  #pragma unroll 1
  for (int c = 0; c < 31; ++c) {   // 124 steps per chain
    const int pfA = (c + 1 < 31) ? sA + 4 : sA;  // in-bounds prefetch
    const int pfB = (c + 1 < 31) ? sB + 4 : sB;
    mknA = *(const f4*)(mkb + pfA);
    mknB = *(const f4*)(mkb + pfB);
    STEP(BfA, McA, cntA, sA + 0, mkA[0], false, shPA);
    STEP(BfB, McB, cntB, sB + 0, mkB[0], false, shPB);
    STEP(BfA, McA, cntA, sA + 1, mkA[1], true,  shPA);  MEASURE(BfA, shAA);
    STEP(BfB, McB, cntB, sB + 1, mkB[1], true,  shPB);  MEASURE(BfB, shAB);
    STEP(BfA, McA, cntA, sA + 2, mkA[2], false, shPA);
    STEP(BfB, McB, cntB, sB + 2, mkB[2], false, shPB);
    STEP(BfA, McA, cntA, sA + 3, mkA[3], true,  shAA);  MEASURE(BfA, shPA);
    STEP(BfB, McB, cntB, sB + 3, mkB[3], true,  shAB);  MEASURE(BfB, shPB);
    mkA = mknA; mkB = mknB;
    sA += 4; sB += 4;
  }
  // epilogue: steps 124..127 of each chain; scalar masks; B guarded (wid 3).
  STEP(BfA, McA, cntA, sA + 0, mkb[sA + 0], false, shPA);
  if (sB + 0 < Sn) STEP(BfB, McB, cntB, sB + 0, mkb[sB + 0], false, shPB);
  STEP(BfA, McA, cntA, sA + 1, mkb[sA + 1], true, shPA);  MEASURE(BfA, shAA);
  if (sB + 1 < Sn) { STEP(BfB, McB, cntB, sB + 1, mkb[sB + 1], true, shPB); MEASURE(BfB, shAB); }
  STEP(BfA, McA, cntA, sA + 2, mkb[sA + 2], false, shPA);
  if (sB + 2 < Sn) STEP(BfB, McB, cntB, sB + 2, mkb[sB + 2], false, shPB);
  STEP(BfA, McA, cntA, sA + 3, mkb[sA + 3], true, shAA);
  if (sB + 3 < Sn) STEP(BfB, McB, cntB, sB + 3, mkb[sB + 3], true, shAB);

  // ---- register-resident combine: 8 turns, wave t>>1 applies chain t&1 ----
  const float addcA = (mtg + 6.0f) * cntA;
  const float addcB = (mtg + 6.0f) * cntB;
  if (wid == 0 && l < Tn) lwbuf[l] = (startt[l] + emb[l]) * LOG2E;
  __syncthreads();

  auto APPLYM = [&](h8 (&Bf)[2][3], float (&Mc)[3], float addc) {
    const float u0 = lwbuf[c16]      + Mc[0] + addc;
    const float u1 = lwbuf[16 + c16] + Mc[1] + addc;
    const float u2 = lwbuf[32 + c16] + Mc[2] + addc;
    float um = fmaxf(u0, fmaxf(u1, u2));
    #pragma unroll
    for (int off = 1; off < 64; off <<= 1) um = fmaxf(um, __shfl_xor(um, off));
    const float p0 = __builtin_amdgcn_exp2f(u0 - um);
    const float p1 = __builtin_amdgcn_exp2f(u1 - um);
    const float p2 = __builtin_amdgcn_exp2f(u2 - um);
    float rs0[8], rs1[4];
    #pragma unroll
    for (int i = 0; i < 8; ++i) {
      float v = (float)Bf[0][0][i] * p0;
      v = fmaf((float)Bf[0][1][i], p1, v);
      v = fmaf((float)Bf[0][2][i], p2, v);
      #pragma unroll
      for (int off = 1; off < 16; off <<= 1) v += __shfl_xor(v, off);
      rs0[i] = v;
    }
    #pragma unroll
    for (int i = 0; i < 4; ++i) {
      float v = (float)Bf[1][0][i] * p0;
      v = fmaf((float)Bf[1][1][i], p1, v);
      v = fmaf((float)Bf[1][2][i], p2, v);
      #pragma unroll
      for (int off = 1; off < 16; off <<= 1) v += __shfl_xor(v, off);
      rs1[i] = v;
    }
    if (c16 == 0) {
      #pragma unroll
      for (int i = 0; i < 4; ++i) {
        lwbuf[4 * g + i]       = um + __builtin_amdgcn_logf(rs0[i]);       // k=4g+i
        lwbuf[16 + 4 * g + i]  = um + __builtin_amdgcn_logf(rs0[i + 4]);   // k=16+4g+i
        lwbuf[32 + 4 * g + i]  = um + __builtin_amdgcn_logf(rs1[i]);       // k=32+4g+i
      }
    }
  };

  #pragma unroll 1
  for (int t = 0; t < NSEG; ++t) {
    if ((t & 1) == 0) {
      if (wid == (t >> 1)) APPLYM(BfA, McA, addcA);
    } else {
      if (wid == (t >> 1)) APPLYM(BfB, McB, addcB);
    }
    __syncthreads();
  }

  // ---- final: den = lse_j(lw[j] + end2[j]) * ln2 ----
  if (wid == 0) {
    float v = (l < Tn) ? lwbuf[l] + endt[l] * LOG2E : -INFINITY;
    float mv = v;
    #pragma unroll
    for (int off = 32; off; off >>= 1) mv = fmaxf(mv, __shfl_xor(mv, off));
    float zz = (l < Tn) ? __builtin_amdgcn_exp2f(v - mv) : 0.f;
    #pragma unroll
    for (int off = 32; off; off >>= 1) zz += __shfl_xor(zz, off);
    if (l == 0) den_out[b] = (mv + __builtin_amdgcn_logf(zz)) * LN2f;
  }
}

// Numerator: no recurrence -> fully parallel gather+reduce. One block per batch.
__global__ __launch_bounds__(256) void crf_numer(
    const float* __restrict__ em, const int* __restrict__ tags,
    const float* __restrict__ mask, const float* __restrict__ trans,
    const float* __restrict__ startt, const float* __restrict__ endt,
    float* __restrict__ num_out)
{
  const int b = blockIdx.x, t = threadIdx.x;
  const int*   tgb = tags + (size_t)b * Sn;
  const float* mkb = mask + (size_t)b * Sn;
  const float* emb = em + (size_t)b * Sn * Tn;

  const int s0 = t * 4;
  const int4 tg = *(const int4*)(tgb + s0);
  const f4   mk = *(const f4*)(mkb + s0);
  const int  tprev = (t == 0) ? 0 : tgb[s0 - 1];
  const int  tgarr[5] = {tprev, tg.x, tg.y, tg.z, tg.w};

  float acc  = 0.0f;
  float msum = mk[0] + mk[1] + mk[2] + mk[3];
  #pragma unroll
  for (int i = 0; i < 4; ++i) {
    const int s = s0 + i;
    if (s >= 1)
      acc += mk[i] * (emb[(size_t)s * Tn + tgarr[i + 1]] +
                      trans[tgarr[i + 1] * Tn + tgarr[i]]);
  }
  #pragma unroll
  for (int off = 32; off; off >>= 1) {
    acc  += __shfl_xor(acc, off);
    msum += __shfl_xor(msum, off);
  }
  __shared__ float ra[4], rm[4];
  if ((t & 63) == 0) { ra[t >> 6] = acc; rm[t >> 6] = msum; }
  __syncthreads();
  if (t == 0) {
    const float a = ra[0] + ra[1] + ra[2] + ra[3];
    const float m = rm[0] + rm[1] + rm[2] + rm[3];
    int last = (int)(m + 0.5f) - 1;
    if (last < 0) last = 0;
    const int lt = tgb[last];
    const int t0 = tgb[0];
    num_out[b] = startt[t0] + emb[t0] + a + endt[lt];
  }
}

__global__ __launch_bounds__(512) void reduce_loss(const float* __restrict__ den,
                                                   const float* __restrict__ num,
                                                   float* __restrict__ out) {
  __shared__ float red[8];
  const int t = threadIdx.x;
  float v = den[t] - num[t];
  #pragma unroll
  for (int off = 32; off; off >>= 1) v += __shfl_xor(v, off);
  if ((t & 63) == 0) red[t >> 6] = v;
  __syncthreads();
  if (t == 0) {
    float s = 0.f;
    #pragma unroll
    for (int wv = 0; wv < 8; ++wv) s += red[wv];
    out[0] = s * (1.0f / 512.0f);
  }
}

extern "C" void kernel_launch(void* const* d_in, const int* in_sizes, int n_in,
                              void* d_out, int out_size, void* d_ws, size_t ws_size,
                              hipStream_t stream) {
  const float* emissions = (const float*)d_in[0];
  const int*   tags      = (const int*)d_in[1];
  const float* mask      = (const float*)d_in[2];
  const float* trans     = (const float*)d_in[3];
  const float* startt    = (const float*)d_in[4];
  const float* endt      = (const float*)d_in[5];
  float* den_ws = (float*)d_ws;         // 512 floats
  float* num_ws = den_ws + Bn;          // 512 floats
  const size_t ehoff   = 4096;
  const size_t ehbytes = (size_t)Bn * Sn * Tn * sizeof(_Float16);
  _Float16* eh16 = (_Float16*)((char*)d_ws + ehoff);
  const bool pre = (ws_size >= ehoff + ehbytes);

  crf_numer<<<Bn, 256, 0, stream>>>(emissions, tags, mask, trans, startt, endt, num_ws);
  if (pre) {
    const int total8 = Bn * Sn * Tn / 8;
    ehgen<<<(total8 + 255) / 256, 256, 0, stream>>>(emissions, eh16);
    crf_fwd_seg<true><<<Bn, 256, 0, stream>>>(emissions, mask, trans, startt, endt,
                                              eh16, den_ws);
  } else {
    crf_fwd_seg<false><<<Bn, 256, 0, stream>>>(emissions, mask, trans, startt, endt,
                                               nullptr, den_ws);
  }
  reduce_loss<<<1, 512, 0, stream>>>(den_ws, num_ws, (float*)d_out);
}